// Round 12
// baseline (221.029 us; speedup 1.0000x reference)
//
#include <hip/hip_runtime.h>

#define NB   32
#define H    1024
#define W    1024
#define BAND 8               // output rows per band (bucket granularity)
#define NBANDS (H / BAND)    // 128 band buckets per image (topk unchanged)
#define BGRP 4               // bands per block (rolling window)
#define NGRP (NBANDS / BGRP) // 32 block-groups per image
#define TOPK 200
#define NMS_THRESH 0.1f
#define HI_THRESH  0.999f    // fast-path split; exact fallback preserved
#define CAPH 32              // hi keys per band bucket (E~7)
#define LBL  320             // LDS lo keys per band (E~150, +14 sigma)

typedef unsigned long long ull;
typedef float f4 __attribute__((ext_vector_type(4)));

__device__ __forceinline__ f4 fmax4(f4 a, f4 b) {
    f4 r;
    r.x = fmaxf(a.x, b.x); r.y = fmaxf(a.y, b.y);
    r.z = fmaxf(a.z, b.z); r.w = fmaxf(a.w, b.w);
    return r;
}
__device__ __forceinline__ f4 shfl_up4(f4 v) {
    f4 r;
    r.x = __shfl_up(v.x, 1); r.y = __shfl_up(v.y, 1);
    r.z = __shfl_up(v.z, 1); r.w = __shfl_up(v.w, 1);
    return r;
}
__device__ __forceinline__ f4 shfl_dn4(f4 v) {
    f4 r;
    r.x = __shfl_down(v.x, 1); r.y = __shfl_down(v.y, 1);
    r.z = __shfl_down(v.z, 1); r.w = __shfl_down(v.w, 1);
    return r;
}

// ---------------- Phase 1: 7x7 NMS, 4-band rolling blocks ----------------
// R9-R11 accounting: marginal loads 35us, compute free, emit variants all
// within 4us of each other -> peak's 77-35=42us is PER-BLOCK FIXED cost
// (4096 blocks, 16 sequential rounds/CU: prologue, unamortized load
// latency, barrier convoys, retire drain) + 1.75x halo redundancy.
// Fix both: each block = 4 consecutive bands, rolling 14-row register
// window (band 0: 14 loads, bands 1-3: +8 each) -> 38 rows / 32 output
// rows = 1.19x halo (-32% lane requests), 1024 blocks (4x fewer, all
// co-resident at ~4/CU). Emit = R7-proven per-thread LDS atomic form,
// per-band partitioned buffers, 1 sync/band + 1 pre-flush. Buckets and
// topk kernel UNCHANGED.
__global__ __launch_bounds__(256) void peak_kernel(
    const float* __restrict__ in,
    ull* __restrict__ cand_hi,   // [NB*NBANDS][CAPH]
    ull* __restrict__ cand_lo,   // [NB*NBANDS][capl]
    int* __restrict__ cntl,      // [NB*NBANDS], clamped counts
    int* __restrict__ cnth,      // [NB*NBANDS], -1 => hi overflow -> lo path
    int capl)
{
    __shared__ f4 edge[BGRP][BAND][4][2];   // 4 KB: per-band wave-boundary quads
    __shared__ ull lb_lo[BGRP][LBL];        // 10 KB
    __shared__ ull lb_hi[BGRP][CAPH];       // 1 KB
    __shared__ int lc_lo[BGRP], lc_hi[BGRP];

    const int img = blockIdx.y;
    const int grp = blockIdx.x;
    const int Rb  = grp * (BGRP * BAND);    // first output row of group
    const char* base = (const char*)(in + ((size_t)img << 20));
    const int t = threadIdx.x;
    const int lane = t & 63;
    const int wv   = t >> 6;

    if (t < BGRP) { lc_lo[t] = 0; lc_hi[t] = 0; }

    const int cb = t << 4;   // own quad byte offset

    // ---- initial window: rows Rb-3 .. Rb+10 (clamped) ----
    f4 win[14];
    #pragma unroll
    for (int r = 0; r < 14; r++) {
        const int ri = min(max(Rb - 3 + r, 0), H - 1);
        win[r] = *(const f4*)(base + ((size_t)ri << 12) + cb);
    }

    #pragma unroll
    for (int bi = 0; bi < BGRP; bi++) {
        const int R0 = Rb + bi * BAND;
        // invariant: win[0..13] = input rows R0-3 .. R0+10 (clamped)

        // ---- vertical 7-max in registers; stash wave-boundary quads ----
        f4 acc[BAND];
        #pragma unroll
        for (int ro = 0; ro < BAND; ro++) {
            f4 a = fmax4(fmax4(fmax4(win[ro], win[ro + 1]),
                               fmax4(win[ro + 2], win[ro + 3])),
                         fmax4(fmax4(win[ro + 4], win[ro + 5]), win[ro + 6]));
            acc[ro] = a;
            if (lane == 0)  edge[bi][ro][wv][0] = a;
            if (lane == 63) edge[bi][ro][wv][1] = a;
        }
        __syncthreads();   // edge quads (and, for bi=0, lc init) visible

        // ---- horizontal 7-max via shuffles + peak emit (R7 form) ----
        #pragma unroll
        for (int ro = 0; ro < BAND; ro++) {
            f4 a  = acc[ro];
            f4 lq = shfl_up4(a);
            f4 rq = shfl_dn4(a);
            if (lane == 0) {
                lq = a;
                if (t != 0) lq = edge[bi][ro][wv - 1][1];
            }
            if (lane == 63) {
                rq = a;
                if (t != 255) rq = edge[bi][ro][wv + 1][0];
            }
            float S3 = a.x;
            float S2 = fmaxf(lq.w, S3);
            float S1 = fmaxf(lq.z, S2);
            float S0 = fmaxf(lq.y, S1);
            float P5 = fmaxf(a.y, a.z);
            float P6 = fmaxf(P5, a.w);
            float P7 = fmaxf(P6, rq.x);
            float P8 = fmaxf(P7, rq.y);
            float P9 = fmaxf(P8, rq.z);
            float w0 = fmaxf(S0, P6), w1 = fmaxf(S1, P7);
            float w2 = fmaxf(S2, P8), w3 = fmaxf(S3, P9);
            f4 ctr = win[ro + 3];
            const int rg = R0 + ro;
            bool p0 = (ctr.x > NMS_THRESH) && (ctr.x == w0);
            bool p1 = (ctr.y > NMS_THRESH) && (ctr.y == w1);
            bool p2 = (ctr.z > NMS_THRESH) && (ctr.z == w2);
            bool p3 = (ctr.w > NMS_THRESH) && (ctr.w == w3);
            int cnt = (int)p0 + (int)p1 + (int)p2 + (int)p3;
            if (cnt) {                                // rare (~8%/thread-row)
                int s = atomicAdd(&lc_lo[bi], cnt);
                unsigned ib = ((unsigned)rg << 10) | ((unsigned)t << 2);
                float cv[4] = {ctr.x, ctr.y, ctr.z, ctr.w};
                bool  pp[4] = {p0, p1, p2, p3};
                #pragma unroll
                for (int j = 0; j < 4; j++) {
                    if (pp[j]) {
                        ull key = ((ull)__float_as_uint(cv[j]) << 32) |
                                  (ull)(0xFFFFFFFFu - (ib + j));
                        if (s < LBL) lb_lo[bi][s] = key;
                        s++;
                        if (cv[j] > HI_THRESH) {
                            int q = atomicAdd(&lc_hi[bi], 1);
                            if (q < CAPH) lb_hi[bi][q] = key;
                        }
                    }
                }
            }
        }

        // ---- roll window: keep rows R0+5..R0+10, load R0+11..R0+18 ----
        if (bi < BGRP - 1) {
            #pragma unroll
            for (int j = 0; j < 6; j++) win[j] = win[j + 8];
            #pragma unroll
            for (int k = 0; k < 8; k++) {
                const int ri = min(R0 + 11 + k, H - 1);
                win[6 + k] = *(const f4*)(base + ((size_t)ri << 12) + cb);
            }
        }
    }

    // ---- flush all 4 band buckets (coalesced, R7 form) ----
    __syncthreads();
    #pragma unroll
    for (int bi = 0; bi < BGRP; bi++) {
        const int bkt = img * NBANDS + grp * BGRP + bi;
        const int nl_raw = lc_lo[bi], nh_raw = lc_hi[bi];
        const int nl = min(nl_raw, min(LBL, capl));
        const int nh = min(nh_raw, CAPH);
        ull* glo = cand_lo + (size_t)bkt * capl;
        for (int i = t; i < nl; i += 256) glo[i] = lb_lo[bi][i];
        ull* ghi = cand_hi + (size_t)bkt * CAPH;
        if (t < nh) ghi[t] = lb_hi[bi][t];
        if (t == 0) {
            cntl[bkt] = nl;
            cnth[bkt] = (nh_raw > CAPH) ? -1 : nh_raw;
        }
    }
}

// ---------------- Phase 2: per-image exact top-200 ----------------
// Byte-identical to the R3/R7-verified kernel (~17us): AND/OR prefix skip,
// early-exit radix, shuffle suffix-scan, rank-select.
__global__ __launch_bounds__(256) void topk_kernel(
    const ull* __restrict__ cand_hi,
    const ull* __restrict__ cand_lo,
    const int* __restrict__ cntl,
    const int* __restrict__ cnth,
    float* __restrict__ out,
    int capl)
{
    const int img = blockIdx.x;
    const int t = threadIdx.x;
    const int wv = t >> 6;
    const int lane = t & 63;
    __shared__ ull stage[NBANDS * CAPH];   // 32 KB: all hi keys fit
    __shared__ unsigned hist[4][256];      // wave-private histograms
    __shared__ unsigned sfx[256];
    __shared__ ull sel[256];
    __shared__ int s_ch[NBANDS], s_cl[NBANDS], s_oh[NBANDS + 1];
    __shared__ int s_ok;
    __shared__ int scnt;
    __shared__ unsigned s_pref;
    __shared__ int s_k, s_stop;
    __shared__ unsigned aW[4], oW[4], s_and, s_or, wsum[4];

    if (t == 0) { s_ok = 1; s_stop = 0; scnt = 0; }
    __syncthreads();
    if (t < NBANDS) {
        int raw = cnth[img * NBANDS + t];
        s_ch[t] = max(raw, 0);
        s_cl[t] = cntl[img * NBANDS + t];
        if (raw < 0) s_ok = 0;       // benign race: all writers store 0
    }
    __syncthreads();
    if (t == 0) {
        int a = 0;
        for (int b = 0; b < NBANDS; b++) { s_oh[b] = a; a += s_ch[b]; }
        s_oh[NBANDS] = a;
    }
    __syncthreads();
    const int nh = s_oh[NBANDS];
    const bool use_hi = (nh >= TOPK) && (s_ok != 0);

    if (use_hi) {
        int b = t >> 1, i0 = t & 1;              // 2 threads per band
        int nb = s_ch[b], ob = s_oh[b];
        const ull* p = cand_hi + (size_t)(img * NBANDS + b) * CAPH;
        for (int i = i0; i < nb; i += 2) stage[ob + i] = p[i];
    }
    __syncthreads();

    int n_tot = nh;
    if (!use_hi) {
        n_tot = 0;
        for (int b = 0; b < NBANDS; b++) n_tot += s_cl[b];
    }

    unsigned T = 0;   // value-bits threshold (partial or exact)
    if (n_tot > 256) {
        // ---- AND/OR over candidate value bits -> common high-byte prefix
        unsigned va = 0xFFFFFFFFu, vo = 0u;
        if (use_hi) {
            for (int i = t; i < nh; i += 256) {
                unsigned vb = (unsigned)(stage[i] >> 32);
                va &= vb; vo |= vb;
            }
        } else {
            for (int b = 0; b < NBANDS; b++) {
                int nb = s_cl[b];
                const ull* p = cand_lo + (size_t)(img * NBANDS + b) * capl;
                for (int i = t; i < nb; i += 256) {
                    unsigned vb = (unsigned)(p[i] >> 32);
                    va &= vb; vo |= vb;
                }
            }
        }
        #pragma unroll
        for (int off = 32; off > 0; off >>= 1) {
            va &= __shfl_xor(va, off);
            vo |= __shfl_xor(vo, off);
        }
        if (lane == 0) { aW[wv] = va; oW[wv] = vo; }
        __syncthreads();
        if (t == 0) {
            unsigned A = 0xFFFFFFFFu, O = 0u;
            for (int w = 0; w < 4; w++) { A &= aW[w]; O |= oW[w]; }
            s_and = A; s_or = O;
        }
        __syncthreads();
        const unsigned diff = s_and ^ s_or;
        int sb = 3;
        unsigned maskhi = 0u;
        while (sb >= 0 && ((diff >> (sb * 8)) & 0xFFu) == 0u) {
            maskhi |= 0xFFu << (sb * 8);
            sb--;
        }
        unsigned prefix = s_and & maskhi;

        if (sb < 0) {
            T = s_and;               // all candidate values identical
        } else {
            int kk = TOPK;
            for (int byte = sb; byte >= 0; byte--) {
                #pragma unroll
                for (int w = 0; w < 4; w++) hist[w][t] = 0;
                __syncthreads();
                const int shift = byte * 8;
                if (use_hi) {
                    for (int i = t; i < nh; i += 256) {
                        unsigned vb = (unsigned)(stage[i] >> 32);
                        if ((vb & maskhi) == prefix)
                            atomicAdd(&hist[wv][(vb >> shift) & 0xFFu], 1u);
                    }
                } else {
                    for (int b = 0; b < NBANDS; b++) {
                        int nb = s_cl[b];
                        const ull* p = cand_lo + (size_t)(img * NBANDS + b) * capl;
                        for (int i = t; i < nb; i += 256) {
                            unsigned vb = (unsigned)(p[i] >> 32);
                            if ((vb & maskhi) == prefix)
                                atomicAdd(&hist[wv][(vb >> shift) & 0xFFu], 1u);
                        }
                    }
                }
                __syncthreads();
                // suffix-scan of 256 bins: wave shuffle (2 barriers)
                unsigned v = hist[0][t] + hist[1][t] + hist[2][t] + hist[3][t];
                #pragma unroll
                for (int off = 1; off < 64; off <<= 1) {
                    unsigned u = __shfl_down(v, off);
                    if (lane + off < 64) v += u;
                }
                if (lane == 0) wsum[wv] = v;
                __syncthreads();
                unsigned add = 0;
                for (int w = wv + 1; w < 4; w++) add += wsum[w];
                unsigned myfx = v + add;         // count(matching, byte >= t)
                sfx[t] = myfx;
                __syncthreads();
                unsigned nxt = (t == 255) ? 0u : sfx[t + 1];
                if (myfx >= (unsigned)kk && nxt < (unsigned)kk) {
                    s_pref = prefix | ((unsigned)t << shift);
                    s_k = kk - (int)nxt;
                    // candidates {vb >= new partial T} = (TOPK-kk) + myfx
                    if ((TOPK - kk) + (int)myfx <= 256) s_stop = 1;
                }
                __syncthreads();
                prefix = s_pref;
                kk = s_k;
                maskhi |= (0xFFu << shift);
                if (s_stop) break;
            }
            T = prefix;
        }
    }

    __syncthreads();
    if (use_hi) {
        for (int i = t; i < nh; i += 256) {
            ull k = stage[i];
            if ((unsigned)(k >> 32) >= T) {
                int s = atomicAdd(&scnt, 1);
                if (s < 256) sel[s] = k;
            }
        }
    } else {
        for (int b = 0; b < NBANDS; b++) {
            int nb = s_cl[b];
            const ull* p = cand_lo + (size_t)(img * NBANDS + b) * capl;
            for (int i = t; i < nb; i += 256) {
                ull k = p[i];
                if ((unsigned)(k >> 32) >= T) {
                    int s = atomicAdd(&scnt, 1);
                    if (s < 256) sel[s] = k;
                }
            }
        }
    }
    __syncthreads();
    const int m = min(scnt, 256);
    ull* sorted = stage;               // stage is dead past this point
    if (t >= m) sel[t] = 0ull;
    sorted[t] = 0ull;
    __syncthreads();

    // ---- rank-select: exact descending order of unique full keys ----
    {
        ull k = sel[t];
        int rank = 0;
        for (int j = 0; j < 256; j++) rank += (sel[j] > k) ? 1 : 0;
        if (k != 0ull && rank < 256) sorted[rank] = k;
    }
    __syncthreads();

    // write: coords [NB,TOPK,2] then probs [NB,TOPK], all fp32
    if (t < TOPK) {
        ull key = sorted[t];
        float prob = 0.0f;
        unsigned row = 0, col = 0;
        if (key != 0ull) {
            prob = __uint_as_float((unsigned)(key >> 32));
            unsigned idx = 0xFFFFFFFFu - (unsigned)(key & 0xFFFFFFFFull);
            row = idx >> 10;
            col = idx & (W - 1);
        }
        size_t cbase = (size_t)img * TOPK * 2 + (size_t)t * 2;
        out[cbase + 0] = (float)row;
        out[cbase + 1] = (float)col;
        out[(size_t)NB * TOPK * 2 + (size_t)img * TOPK + t] = prob;
    }
}

extern "C" void kernel_launch(void* const* d_in, const int* in_sizes, int n_in,
                              void* d_out, int out_size, void* d_ws, size_t ws_size,
                              hipStream_t stream) {
    const float* center_map = (const float*)d_in[0];
    float* out = (float*)d_out;

    // workspace layout (counts plain-stored by peak_kernel; NO memset):
    //   [0, 16K)      : cntl[4096]
    //   [16K, 32K)    : cnth[4096]
    //   [32K, +1M)    : cand_hi[4096][CAPH]
    //   rest          : cand_lo[4096][capl]
    const int nbkt = NB * NBANDS;   // 4096
    int* cntl = (int*)d_ws;
    int* cnth = (int*)((char*)d_ws + 16384);
    ull* cand_hi = (ull*)((char*)d_ws + 32768);
    size_t hi_bytes = (size_t)nbkt * CAPH * sizeof(ull);   // 1 MB
    ull* cand_lo = (ull*)((char*)d_ws + 32768 + hi_bytes);
    size_t avail = (ws_size > 32768 + hi_bytes) ? (ws_size - 32768 - hi_bytes) : 0;
    int capl = (int)(avail / (nbkt * sizeof(ull)));
    if (capl > LBL) capl = LBL;
    if (capl < 1) capl = 1;

    dim3 gridA(NGRP, NB);   // 32 x 32 = 1024 blocks, 4 bands each
    peak_kernel<<<gridA, 256, 0, stream>>>(center_map, cand_hi, cand_lo,
                                           cntl, cnth, capl);

    topk_kernel<<<NB, 256, 0, stream>>>(cand_hi, cand_lo, cntl, cnth, out, capl);
}

// Round 13
// 200.349 us; speedup vs baseline: 1.1032x; 1.1032x over previous
//
#include <hip/hip_runtime.h>

#define NB   32
#define H    1024
#define W    1024
#define BAND 8               // output rows per block
#define NBANDS (H / BAND)    // 128 bands per image
#define NROWS 14             // input rows per block (BAND + 6 halo)
#define TOPK 200
#define NMS_THRESH 0.1f
#define HI_THRESH  0.999f    // hi split: every hi value > any non-hi value
#define CAPH 32              // hi keys per band bucket (E~8, P(ovfl)~1e-12)

typedef unsigned long long ull;
typedef float f4 __attribute__((ext_vector_type(4)));

__device__ __forceinline__ f4 fmax4(f4 a, f4 b) {
    f4 r;
    r.x = fmaxf(a.x, b.x); r.y = fmaxf(a.y, b.y);
    r.z = fmaxf(a.z, b.z); r.w = fmaxf(a.w, b.w);
    return r;
}
__device__ __forceinline__ f4 shfl_up4(f4 v) {
    f4 r;
    r.x = __shfl_up(v.x, 1); r.y = __shfl_up(v.y, 1);
    r.z = __shfl_up(v.z, 1); r.w = __shfl_up(v.w, 1);
    return r;
}
__device__ __forceinline__ f4 shfl_dn4(f4 v) {
    f4 r;
    r.x = __shfl_down(v.x, 1); r.y = __shfl_down(v.y, 1);
    r.z = __shfl_down(v.z, 1); r.w = __shfl_down(v.w, 1);
    return r;
}

// ---------------- Phase 1: 7x7 NMS, hi-only emission ----------------
// R9 ablation: loads+compute = 33.5us marginal; R7 full kernel ~72us; the
// delta survived every micro-fix (atomics R11, global-vs-LDS R10, block
// count R12, MLP R8) -> remaining suspect is the LO-PATH MACHINERY IN
// AGGREGATE (code footprint, 3KB buffer, per-thread bookkeeping, flush,
// 10.9MB of retired stores). Deleted here: only hi keys (> 0.999) are
// emitted (~1030/image, <=32/block; P(emit per thread-row) ~0.4%).
// Exact because top-200 is provably inside the hi set whenever
// nh >= 200 and no bucket overflowed (every hi value > any non-hi value);
// otherwise topk runs a full exact recompute fallback (below).
// Loads/vmax/shuffles BYTE-IDENTICAL to R7 (best, 203.8us).
__global__ __launch_bounds__(256) void peak_kernel(
    const float* __restrict__ in,
    ull* __restrict__ cand_hi,   // [NB*NBANDS][CAPH]
    int* __restrict__ cnth)      // [NB*NBANDS], -1 => overflow -> fallback
{
    __shared__ f4 edge[BAND][4][2];      // 1 KB: per-wave boundary quads
    __shared__ ull lb_hi[CAPH];          // 256 B
    __shared__ int lc_hi;

    const int img  = blockIdx.y;
    const int band = blockIdx.x;
    const int R0   = band * BAND;
    const char* base = (const char*)(in + ((size_t)img << 20));
    const int t = threadIdx.x;
    const int lane = t & 63;
    const int wv   = t >> 6;

    if (t == 0) lc_hi = 0;

    const int cb = t << 4;   // own quad byte offset

    // ---- 14 own-quad loads ----
    f4 oq[NROWS];
    #pragma unroll
    for (int r = 0; r < NROWS; r++) {
        const int ri = min(max(R0 - 3 + r, 0), H - 1);   // exact row clamp
        oq[r] = *(const f4*)(base + ((size_t)ri << 12) + cb);
    }

    // ---- vertical 7-max in registers; stash wave-boundary quads ----
    f4 acc[BAND];
    #pragma unroll
    for (int ro = 0; ro < BAND; ro++) {
        f4 a = fmax4(fmax4(fmax4(oq[ro], oq[ro + 1]),
                           fmax4(oq[ro + 2], oq[ro + 3])),
                     fmax4(fmax4(oq[ro + 4], oq[ro + 5]), oq[ro + 6]));
        acc[ro] = a;
        if (lane == 0)  edge[ro][wv][0] = a;
        if (lane == 63) edge[ro][wv][1] = a;
    }
    __syncthreads();   // edge quads + lc init visible

    // ---- horizontal 7-max via shuffles + hi-only emit ----
    #pragma unroll
    for (int ro = 0; ro < BAND; ro++) {
        f4 a  = acc[ro];
        f4 lq = shfl_up4(a);          // lane-1's quad = cols 4t-4..4t-1
        f4 rq = shfl_dn4(a);          // lane+1's quad = cols 4t+4..4t+7
        if (lane == 0) {              // cross-wave / global-left clamp
            lq = a;
            if (t != 0) lq = edge[ro][wv - 1][1];
        }
        if (lane == 63) {             // cross-wave / global-right clamp
            rq = a;
            if (t != 255) rq = edge[ro][wv + 1][0];
        }
        float S3 = a.x;
        float S2 = fmaxf(lq.w, S3);
        float S1 = fmaxf(lq.z, S2);
        float S0 = fmaxf(lq.y, S1);
        float P5 = fmaxf(a.y, a.z);
        float P6 = fmaxf(P5, a.w);
        float P7 = fmaxf(P6, rq.x);
        float P8 = fmaxf(P7, rq.y);
        float P9 = fmaxf(P8, rq.z);
        float w0 = fmaxf(S0, P6), w1 = fmaxf(S1, P7);
        float w2 = fmaxf(S2, P8), w3 = fmaxf(S3, P9);
        f4 ctr = oq[ro + 3];
        // hi-peak test: > HI_THRESH implies > NMS_THRESH
        bool h0 = (ctr.x > HI_THRESH) && (ctr.x == w0);
        bool h1 = (ctr.y > HI_THRESH) && (ctr.y == w1);
        bool h2 = (ctr.z > HI_THRESH) && (ctr.z == w2);
        bool h3 = (ctr.w > HI_THRESH) && (ctr.w == w3);
        int cnt = (int)h0 + (int)h1 + (int)h2 + (int)h3;
        if (cnt) {                                // ~0.4% of thread-rows
            int s = atomicAdd(&lc_hi, cnt);
            unsigned ib = ((unsigned)(R0 + ro) << 10) | ((unsigned)t << 2);
            float cv[4] = {ctr.x, ctr.y, ctr.z, ctr.w};
            bool  hh[4] = {h0, h1, h2, h3};
            #pragma unroll
            for (int j = 0; j < 4; j++) {
                if (hh[j]) {
                    ull key = ((ull)__float_as_uint(cv[j]) << 32) |
                              (ull)(0xFFFFFFFFu - (ib + j));
                    if (s < CAPH) lb_hi[s] = key;
                    s++;
                }
            }
        }
    }

    // ---- flush: <=32 keys + count ----
    __syncthreads();
    const int bkt = img * NBANDS + band;
    const int nh_raw = lc_hi;
    const int nh = min(nh_raw, CAPH);
    ull* ghi = cand_hi + (size_t)bkt * CAPH;
    if (t < nh) ghi[t] = lb_hi[t];
    if (t == 0)
        cnth[bkt] = (nh_raw > CAPH) ? -1 : nh_raw;   // -1: force fallback
}

// ---- fallback full-image NMS scan (EXACT; dead path on this data) ----
// 256 threads, thread t owns cols [4t,4t+4); rolls over all rows with the
// same clamped-window math as peak_kernel. visit(key) per peak found.
template <typename F>
__device__ void fb_scan(const float* __restrict__ in, int img, F visit) {
    __shared__ f4 fedge[2][4][2];   // double-buffered per-row wave edges
    const char* base = (const char*)(in + ((size_t)img << 20));
    const int t = threadIdx.x;
    const int lane = t & 63, wv = t >> 6;
    const int cb = t << 4;
    for (int r = 0; r < H; r++) {
        f4 vq[7];
        #pragma unroll
        for (int k = 0; k < 7; k++) {
            int ri = min(max(r - 3 + k, 0), H - 1);
            vq[k] = *(const f4*)(base + ((size_t)ri << 12) + cb);
        }
        f4 a = fmax4(fmax4(fmax4(vq[0], vq[1]), fmax4(vq[2], vq[3])),
                     fmax4(fmax4(vq[4], vq[5]), vq[6]));
        const int pb = r & 1;
        if (lane == 0)  fedge[pb][wv][0] = a;
        if (lane == 63) fedge[pb][wv][1] = a;
        __syncthreads();   // one sync/row; double buffer makes it safe
        f4 lq = shfl_up4(a), rq = shfl_dn4(a);
        if (lane == 0)  { lq = a; if (t != 0)   lq = fedge[pb][wv - 1][1]; }
        if (lane == 63) { rq = a; if (t != 255) rq = fedge[pb][wv + 1][0]; }
        float S3 = a.x;
        float S2 = fmaxf(lq.w, S3);
        float S1 = fmaxf(lq.z, S2);
        float S0 = fmaxf(lq.y, S1);
        float P5 = fmaxf(a.y, a.z);
        float P6 = fmaxf(P5, a.w);
        float P7 = fmaxf(P6, rq.x);
        float P8 = fmaxf(P7, rq.y);
        float P9 = fmaxf(P8, rq.z);
        float w0 = fmaxf(S0, P6), w1 = fmaxf(S1, P7);
        float w2 = fmaxf(S2, P8), w3 = fmaxf(S3, P9);
        f4 ctr = vq[3];
        unsigned ib = ((unsigned)r << 10) | ((unsigned)t << 2);
        if (ctr.x > NMS_THRESH && ctr.x == w0)
            visit(((ull)__float_as_uint(ctr.x) << 32) | (ull)(0xFFFFFFFFu - (ib + 0)));
        if (ctr.y > NMS_THRESH && ctr.y == w1)
            visit(((ull)__float_as_uint(ctr.y) << 32) | (ull)(0xFFFFFFFFu - (ib + 1)));
        if (ctr.z > NMS_THRESH && ctr.z == w2)
            visit(((ull)__float_as_uint(ctr.z) << 32) | (ull)(0xFFFFFFFFu - (ib + 2)));
        if (ctr.w > NMS_THRESH && ctr.w == w3)
            visit(((ull)__float_as_uint(ctr.w) << 32) | (ull)(0xFFFFFFFFu - (ib + 3)));
    }
}

// ---------------- Phase 2: per-image exact top-200 ----------------
// Hi path byte-identical to the R3/R7-verified select (~17us): stage,
// AND/OR prefix skip, early-exit radix, rank-select. If the hi set is
// insufficient (never on this data), an exact full recompute runs:
// 64-bit full-key radix select over fb_scan passes (keys unique ->
// threshold selects <=256 including exact tie-break).
__global__ __launch_bounds__(256) void topk_kernel(
    const float* __restrict__ in,
    const ull* __restrict__ cand_hi,
    const int* __restrict__ cnth,
    float* __restrict__ out)
{
    const int img = blockIdx.x;
    const int t = threadIdx.x;
    const int wv = t >> 6;
    const int lane = t & 63;
    __shared__ ull stage[NBANDS * CAPH];   // 32 KB: all hi keys fit
    __shared__ unsigned hist[4][256];      // wave-private histograms
    __shared__ unsigned sfx[256];
    __shared__ ull sel[256];
    __shared__ int s_ch[NBANDS], s_oh[NBANDS + 1];
    __shared__ int s_ok, scnt, s_k, s_stop, s_fbcnt;
    __shared__ unsigned s_pref;
    __shared__ ull s_pref64;
    __shared__ unsigned aW[4], oW[4], s_and, s_or, wsum[4];

    if (t == 0) { s_ok = 1; s_stop = 0; scnt = 0; s_fbcnt = 0; }
    __syncthreads();
    if (t < NBANDS) {
        int raw = cnth[img * NBANDS + t];
        s_ch[t] = max(raw, 0);
        if (raw < 0) s_ok = 0;       // benign race: all writers store 0
    }
    __syncthreads();
    if (t == 0) {
        int a = 0;
        for (int b = 0; b < NBANDS; b++) { s_oh[b] = a; a += s_ch[b]; }
        s_oh[NBANDS] = a;
    }
    __syncthreads();
    const int nh = s_oh[NBANDS];
    const bool use_hi = (nh >= TOPK) && (s_ok != 0);

    if (use_hi) {
        // ================= hi path (R7-verified select) =================
        {
            int b = t >> 1, i0 = t & 1;              // 2 threads per band
            int nb = s_ch[b], ob = s_oh[b];
            const ull* p = cand_hi + (size_t)(img * NBANDS + b) * CAPH;
            for (int i = i0; i < nb; i += 2) stage[ob + i] = p[i];
        }
        __syncthreads();

        unsigned T = 0;
        if (nh > 256) {
            unsigned va = 0xFFFFFFFFu, vo = 0u;
            for (int i = t; i < nh; i += 256) {
                unsigned vb = (unsigned)(stage[i] >> 32);
                va &= vb; vo |= vb;
            }
            #pragma unroll
            for (int off = 32; off > 0; off >>= 1) {
                va &= __shfl_xor(va, off);
                vo |= __shfl_xor(vo, off);
            }
            if (lane == 0) { aW[wv] = va; oW[wv] = vo; }
            __syncthreads();
            if (t == 0) {
                unsigned A = 0xFFFFFFFFu, O = 0u;
                for (int w = 0; w < 4; w++) { A &= aW[w]; O |= oW[w]; }
                s_and = A; s_or = O;
            }
            __syncthreads();
            const unsigned diff = s_and ^ s_or;
            int sb = 3;
            unsigned maskhi = 0u;
            while (sb >= 0 && ((diff >> (sb * 8)) & 0xFFu) == 0u) {
                maskhi |= 0xFFu << (sb * 8);
                sb--;
            }
            unsigned prefix = s_and & maskhi;

            if (sb < 0) {
                T = s_and;
            } else {
                int kk = TOPK;
                for (int byte = sb; byte >= 0; byte--) {
                    #pragma unroll
                    for (int w = 0; w < 4; w++) hist[w][t] = 0;
                    __syncthreads();
                    const int shift = byte * 8;
                    for (int i = t; i < nh; i += 256) {
                        unsigned vb = (unsigned)(stage[i] >> 32);
                        if ((vb & maskhi) == prefix)
                            atomicAdd(&hist[wv][(vb >> shift) & 0xFFu], 1u);
                    }
                    __syncthreads();
                    unsigned v = hist[0][t] + hist[1][t] + hist[2][t] + hist[3][t];
                    #pragma unroll
                    for (int off = 1; off < 64; off <<= 1) {
                        unsigned u = __shfl_down(v, off);
                        if (lane + off < 64) v += u;
                    }
                    if (lane == 0) wsum[wv] = v;
                    __syncthreads();
                    unsigned add = 0;
                    for (int w = wv + 1; w < 4; w++) add += wsum[w];
                    unsigned myfx = v + add;
                    sfx[t] = myfx;
                    __syncthreads();
                    unsigned nxt = (t == 255) ? 0u : sfx[t + 1];
                    if (myfx >= (unsigned)kk && nxt < (unsigned)kk) {
                        s_pref = prefix | ((unsigned)t << shift);
                        s_k = kk - (int)nxt;
                        if ((TOPK - kk) + (int)myfx <= 256) s_stop = 1;
                    }
                    __syncthreads();
                    prefix = s_pref;
                    kk = s_k;
                    maskhi |= (0xFFu << shift);
                    if (s_stop) break;
                }
                T = prefix;
            }
        }

        __syncthreads();
        for (int i = t; i < nh; i += 256) {
            ull k = stage[i];
            if ((unsigned)(k >> 32) >= T) {
                int s = atomicAdd(&scnt, 1);
                if (s < 256) sel[s] = k;
            }
        }
    } else {
        // ====== EXACT fallback: full recompute + 64-bit radix select =====
        fb_scan(in, img, [&](ull key) { atomicAdd(&s_fbcnt, 1); });
        __syncthreads();
        const int ntot = s_fbcnt;

        ull T64 = 0;
        if (ntot > 256) {
            ull prefix = 0, maskhi = 0;
            int kk = TOPK;
            for (int byte = 7; byte >= 0; byte--) {
                #pragma unroll
                for (int w = 0; w < 4; w++) hist[w][t] = 0;
                __syncthreads();
                const int shift = byte * 8;
                fb_scan(in, img, [&](ull key) {
                    if ((key & maskhi) == prefix)
                        atomicAdd(&hist[wv][(unsigned)(key >> shift) & 0xFFu], 1u);
                });
                __syncthreads();
                unsigned v = hist[0][t] + hist[1][t] + hist[2][t] + hist[3][t];
                #pragma unroll
                for (int off = 1; off < 64; off <<= 1) {
                    unsigned u = __shfl_down(v, off);
                    if (lane + off < 64) v += u;
                }
                if (lane == 0) wsum[wv] = v;
                __syncthreads();
                unsigned add = 0;
                for (int w = wv + 1; w < 4; w++) add += wsum[w];
                unsigned myfx = v + add;
                sfx[t] = myfx;
                __syncthreads();
                unsigned nxt = (t == 255) ? 0u : sfx[t + 1];
                if (myfx >= (unsigned)kk && nxt < (unsigned)kk) {
                    s_pref64 = prefix | ((ull)t << shift);
                    s_k = kk - (int)nxt;
                    if ((TOPK - kk) + (int)myfx <= 256) s_stop = 1;
                }
                __syncthreads();
                prefix = s_pref64;
                kk = s_k;
                maskhi |= (0xFFull << shift);
                if (s_stop) break;
            }
            T64 = prefix;
        }
        __syncthreads();
        fb_scan(in, img, [&](ull key) {
            if (key >= T64) {
                int s = atomicAdd(&scnt, 1);
                if (s < 256) sel[s] = key;
            }
        });
    }

    // ---- common tail: rank-select + write ----
    __syncthreads();
    const int m = min(scnt, 256);
    ull* sorted = stage;               // stage is dead past this point
    if (t >= m) sel[t] = 0ull;
    sorted[t] = 0ull;
    __syncthreads();

    {
        ull k = sel[t];
        int rank = 0;
        for (int j = 0; j < 256; j++) rank += (sel[j] > k) ? 1 : 0;
        if (k != 0ull && rank < 256) sorted[rank] = k;
    }
    __syncthreads();

    // write: coords [NB,TOPK,2] then probs [NB,TOPK], all fp32
    if (t < TOPK) {
        ull key = sorted[t];
        float prob = 0.0f;
        unsigned row = 0, col = 0;
        if (key != 0ull) {
            prob = __uint_as_float((unsigned)(key >> 32));
            unsigned idx = 0xFFFFFFFFu - (unsigned)(key & 0xFFFFFFFFull);
            row = idx >> 10;
            col = idx & (W - 1);
        }
        size_t cbase = (size_t)img * TOPK * 2 + (size_t)t * 2;
        out[cbase + 0] = (float)row;
        out[cbase + 1] = (float)col;
        out[(size_t)NB * TOPK * 2 + (size_t)img * TOPK + t] = prob;
    }
}

extern "C" void kernel_launch(void* const* d_in, const int* in_sizes, int n_in,
                              void* d_out, int out_size, void* d_ws, size_t ws_size,
                              hipStream_t stream) {
    const float* center_map = (const float*)d_in[0];
    float* out = (float*)d_out;

    // workspace layout (cnth plain-stored by peak_kernel; NO memset):
    //   [16K, 32K)    : cnth[4096]
    //   [32K, +1M)    : cand_hi[4096][CAPH]
    int* cnth = (int*)((char*)d_ws + 16384);
    ull* cand_hi = (ull*)((char*)d_ws + 32768);

    dim3 gridA(NBANDS, NB);   // 128 x 32 = 4096 blocks
    peak_kernel<<<gridA, 256, 0, stream>>>(center_map, cand_hi, cnth);

    topk_kernel<<<NB, 256, 0, stream>>>(center_map, cand_hi, cnth, out);
}